// Round 4
// baseline (359.051 us; speedup 1.0000x reference)
//
#include <hip/hip_runtime.h>
#include <math.h>

// Single-query MHA, algebraically collapsed:
//   s[l,h] = x_l . p_h         (p_h = Wk_h^T q_h / sqrt(D); k-bias shift cancels in softmax)
//   z_h    = sum_l softmax(s)_lh * x_l
//   attn   = Wv z + bv ; out = Wo attn + bo
// All fp32. No max-subtraction needed: |s| ~ N(0,1), max ~ 5 << 88 (fp32 exp range).
//
// v4: TWO streaming passes over x instead of the fused phase-A/phase-B kernel.
// The fused version's phase-B re-read depended on L2 residency; per-XCD in-flight
// footprint (64 blocks x 64KB = 4MB) == L2 size -> thrash -> ~2x FETCH + miss
// latency inside a barrier-locked loop (~69us vs 21us floor, R2==R3 showed
// shuffles were not the limiter). Two passes are pure streams: pass 2's re-read
// is L3-served (x=134MB < 256MB) or, worst case, a clean HBM stream.

#define L_SEQ   32768
#define E_DIM   1024
#define NHEAD   8
#define HDIM    128
#define WAVES_M 8            // 512 threads

// ---------------- q = Wq x0 + bq : wave-per-output GEMV ----------------
__global__ __launch_bounds__(256) void proj_q(
    const float* __restrict__ W, const float* __restrict__ bias,
    const float* __restrict__ x, float* __restrict__ q)
{
  const int t = threadIdx.x, wave = t >> 6, lane = t & 63;
  const int o = blockIdx.x * 4 + wave;
  const float4* Wr = (const float4*)(W + (size_t)o * E_DIM);
  const float4* xr = (const float4*)x;   // row 0 of x
  float a = 0.f;
#pragma unroll
  for (int k = 0; k < 4; ++k) {
    float4 wv = Wr[lane + 64 * k];
    float4 xv = xr[lane + 64 * k];
    a += wv.x * xv.x + wv.y * xv.y + wv.z * xv.z + wv.w * xv.w;
  }
#pragma unroll
  for (int m = 1; m < 64; m <<= 1) a += __shfl_xor(a, m, 64);
  if (lane == 0) q[o] = a + bias[o];
}

// ---------------- P_T[h][e] = (1/sqrt(D)) sum_d q[h*128+d] * Wk[h*128+d][e] ----------------
__global__ __launch_bounds__(128) void make_p(
    const float* __restrict__ W, const float* __restrict__ q,
    float* __restrict__ P_T)
{
  const int h = blockIdx.y;
  const int e = blockIdx.x * 128 + threadIdx.x;
  const float* qh = q + h * HDIM;                              // lane-uniform (scalarized)
  const float* Wb = W + ((size_t)E_DIM + (size_t)h * HDIM) * E_DIM + e;  // Wk block rows
  float a0 = 0.f, a1 = 0.f, a2 = 0.f, a3 = 0.f;
#pragma unroll 4
  for (int d = 0; d < HDIM; d += 4) {
    a0 += qh[d + 0] * Wb[(size_t)(d + 0) * E_DIM];
    a1 += qh[d + 1] * Wb[(size_t)(d + 1) * E_DIM];
    a2 += qh[d + 2] * Wb[(size_t)(d + 2) * E_DIM];
    a3 += qh[d + 3] * Wb[(size_t)(d + 3) * E_DIM];
  }
  P_T[h * E_DIM + e] = ((a0 + a1) + (a2 + a3)) * 0.08838834764831845f;   // 1/sqrt(128)
}

// ---------------- pass 1: stream x, write w = exp(x_l . p_h) and block sum-of-w ----------------
// Wave w handles rows {row0 + it*16 + 2w, +1}; no barriers in the hot loop.
// Transpose-butterfly reduce: 16 partials (2 rows x 8 heads) -> 1 per lane, 17 shfl.
__global__ __launch_bounds__(512, 4) void score_pass(
    const float* __restrict__ x,
    const float* __restrict__ P_T,       // [8][1024]
    float* __restrict__ wbuf,            // [L][8]  = exp(scores)
    float* __restrict__ partial_sumw,    // [nblk][8]
    int rows_per_blk)
{
  __shared__ __align__(16) float P_lds[NHEAD * E_DIM];        // 32 KB
  __shared__ __align__(16) float sw_stage[WAVES_M][NHEAD];

  const int t = threadIdx.x;
  const int wave = t >> 6;
  const int lane = t & 63;
  const size_t row0 = (size_t)blockIdx.x * rows_per_blk;
  const int iters = rows_per_blk >> 4;   // 16 rows per iteration (2 per wave)

  // lane -> (row-parity, head) mapping after the transpose reduce:
  // lane ends with value j = b0*8 + b1*4 + b2*2 + b3 (bk = bit k of lane); j = rr*8 + h
  const int rr_l = lane & 1;
  const int h_l = (((lane >> 1) & 1) << 2) | (((lane >> 2) & 1) << 1) | ((lane >> 3) & 1);

  // stage P into LDS (2048 float4 / 512 threads)
  {
    const float4* src = (const float4*)P_T;
    float4* dst = (float4*)P_lds;
#pragma unroll
    for (int i = 0; i < 4; ++i) dst[i * 512 + t] = src[i * 512 + t];
  }
  __syncthreads();

  float sumw_own = 0.f;

  // software-pipelined row loads
  float4 xva[4], xvb[4];
  {
    const size_t trow = row0 + wave * 2;
    const float4* xra = (const float4*)(x + trow * E_DIM);
    const float4* xrb = (const float4*)(x + (trow + 1) * E_DIM);
#pragma unroll
    for (int k = 0; k < 4; ++k) xva[k] = xra[lane + 64 * k];
#pragma unroll
    for (int k = 0; k < 4; ++k) xvb[k] = xrb[lane + 64 * k];
  }

  for (int it = 0; it < iters; ++it) {
    const size_t trow = row0 + (size_t)it * 16 + wave * 2;

    float4 xna[4], xnb[4];
    if (it + 1 < iters) {
      const size_t nrow = trow + 16;
      const float4* xra = (const float4*)(x + nrow * E_DIM);
      const float4* xrb = (const float4*)(x + (nrow + 1) * E_DIM);
#pragma unroll
      for (int k = 0; k < 4; ++k) xna[k] = xra[lane + 64 * k];
#pragma unroll
      for (int k = 0; k < 4; ++k) xnb[k] = xrb[lane + 64 * k];
    }

    float v[16];   // v[h] = row-a partial, v[8+h] = row-b partial
#pragma unroll
    for (int h = 0; h < NHEAD; ++h) {
      const float4* pr = (const float4*)(P_lds + h * E_DIM);
      float a0 = 0.f, a1 = 0.f;
#pragma unroll
      for (int k = 0; k < 4; ++k) {
        float4 p = pr[lane + 64 * k];    // one LDS read feeds both rows
        a0 += xva[k].x * p.x + xva[k].y * p.y + xva[k].z * p.z + xva[k].w * p.w;
        a1 += xvb[k].x * p.x + xvb[k].y * p.y + xvb[k].z * p.z + xvb[k].w * p.w;
      }
      v[h] = a0; v[8 + h] = a1;
    }

    // transpose-butterfly: 4 splitting levels (16->1 values/lane), then 2 plain
#pragma unroll
    for (int lev = 0; lev < 4; ++lev) {
      const int d = 1 << lev;
      const int half = 8 >> lev;
#pragma unroll
      for (int i = 0; i < half; ++i) {
        float lo = v[i], hi = v[i + half];
        float keep = (lane & d) ? hi : lo;
        float oth  = (lane & d) ? lo : hi;
        v[i] = keep + __shfl_xor(oth, d, 64);
      }
    }
    float tot = v[0];
    tot += __shfl_xor(tot, 16, 64);
    tot += __shfl_xor(tot, 32, 64);

    const float w = __expf(tot);
    sumw_own += w;                       // lanes>=16 replicate; only lanes<16 stored
    if (lane < 16) wbuf[(trow + rr_l) * NHEAD + h_l] = w;

    if (it + 1 < iters) {
#pragma unroll
      for (int k = 0; k < 4; ++k) { xva[k] = xna[k]; xvb[k] = xnb[k]; }
    }
  }

  // sum-of-weights: combine row parities, stage per-wave, reduce by first 8 threads
  {
    float s2 = sumw_own + __shfl_xor(sumw_own, 1, 64);
    if (lane < 16 && (lane & 1) == 0) sw_stage[wave][h_l] = s2;
  }
  __syncthreads();
  if (t < NHEAD) {
    float s = 0.f;
#pragma unroll
    for (int wv = 0; wv < WAVES_M; ++wv) s += sw_stage[wv][t];
    partial_sumw[blockIdx.x * NHEAD + t] = s;
  }
}

// ---------------- pass 2: stream x again, accumulate z partials ----------------
// Thread t owns cols {2t, 2t+1} x 8 heads = 16 fp32 accumulators.
// w values staged in LDS once per block (one barrier total).
__global__ __launch_bounds__(512, 4) void accum_pass(
    const float* __restrict__ x,
    const float* __restrict__ wbuf,      // [L][8]
    float* __restrict__ partial_z,       // [nblk][8][1024]
    int rows_per_blk)
{
  __shared__ __align__(16) float w_lds[2048];   // up to 256 rows x 8
  const int t = threadIdx.x;
  const size_t row0 = (size_t)blockIdx.x * rows_per_blk;

  for (int i = t; i < rows_per_blk * NHEAD; i += 512)
    w_lds[i] = wbuf[row0 * NHEAD + i];
  __syncthreads();

  float acc[16];
#pragma unroll
  for (int i = 0; i < 16; ++i) acc[i] = 0.f;

  const float* xb = x + row0 * E_DIM + 2 * t;
  for (int r4 = 0; r4 < rows_per_blk; r4 += 4) {
    float2 xv2[4];
#pragma unroll
    for (int j = 0; j < 4; ++j) xv2[j] = *(const float2*)(xb + (size_t)(r4 + j) * E_DIM);
    float4 wlo[4], whi[4];
#pragma unroll
    for (int j = 0; j < 4; ++j) {
      const float4* wp = (const float4*)&w_lds[(r4 + j) * NHEAD];
      wlo[j] = wp[0]; whi[j] = wp[1];
    }
#pragma unroll
    for (int j = 0; j < 4; ++j) {
      acc[0]  += wlo[j].x * xv2[j].x;  acc[1]  += wlo[j].x * xv2[j].y;
      acc[2]  += wlo[j].y * xv2[j].x;  acc[3]  += wlo[j].y * xv2[j].y;
      acc[4]  += wlo[j].z * xv2[j].x;  acc[5]  += wlo[j].z * xv2[j].y;
      acc[6]  += wlo[j].w * xv2[j].x;  acc[7]  += wlo[j].w * xv2[j].y;
      acc[8]  += whi[j].x * xv2[j].x;  acc[9]  += whi[j].x * xv2[j].y;
      acc[10] += whi[j].y * xv2[j].x;  acc[11] += whi[j].y * xv2[j].y;
      acc[12] += whi[j].z * xv2[j].x;  acc[13] += whi[j].z * xv2[j].y;
      acc[14] += whi[j].w * xv2[j].x;  acc[15] += whi[j].w * xv2[j].y;
    }
  }

  float* zd = partial_z + (size_t)blockIdx.x * (NHEAD * E_DIM) + 2 * t;
#pragma unroll
  for (int h = 0; h < NHEAD; ++h)
    *(float2*)(zd + h * E_DIM) = make_float2(acc[2 * h], acc[2 * h + 1]);
}

// ---------------- reduce partials: zn[h][e] = sum_b pz / sum_b psumw ----------------
__global__ __launch_bounds__(256) void reduce_z(
    const float* __restrict__ partial_z,
    const float* __restrict__ partial_sumw,
    float* __restrict__ zn, int nblk)
{
  __shared__ float red[256];
  __shared__ __align__(16) float swst[4][NHEAD];
  __shared__ float sumw_s[NHEAD];
  const int t = threadIdx.x;
  const int lane = t & 63, wave = t >> 6;

  float sw[NHEAD];
#pragma unroll
  for (int h = 0; h < NHEAD; ++h) sw[h] = 0.f;
  for (int b = t; b < nblk; b += 256) {
    const float4* p = (const float4*)(partial_sumw + (size_t)b * NHEAD);
    float4 a0 = p[0], a1 = p[1];
    sw[0] += a0.x; sw[1] += a0.y; sw[2] += a0.z; sw[3] += a0.w;
    sw[4] += a1.x; sw[5] += a1.y; sw[6] += a1.z; sw[7] += a1.w;
  }
#pragma unroll
  for (int m = 1; m < 64; m <<= 1) {
#pragma unroll
    for (int h = 0; h < NHEAD; ++h) sw[h] += __shfl_xor(sw[h], m, 64);
  }
  if (lane == 0) {
#pragma unroll
    for (int h = 0; h < NHEAD; ++h) swst[wave][h] = sw[h];
  }
  __syncthreads();
  if (t < NHEAD) sumw_s[t] = swst[0][t] + swst[1][t] + swst[2][t] + swst[3][t];

  const int o = blockIdx.x * 32 + (t & 31);
  const int g = t >> 5;
  float a = 0.f;
  for (int b = g; b < nblk; b += 8) a += partial_z[(size_t)b * (NHEAD * E_DIM) + o];
  red[t] = a;
  __syncthreads();
  if (t < 32) {
    float s2 = 0.f;
#pragma unroll
    for (int gg = 0; gg < 8; ++gg) s2 += red[gg * 32 + t];
    const int oo = blockIdx.x * 32 + t;
    zn[oo] = s2 / sumw_s[oo >> 10];   // oo = h*1024 + e
  }
}

// ---------------- attn[o] = Wv[o] . zn[h(o)] + bv[o] ----------------
__global__ __launch_bounds__(256) void proj_v(
    const float* __restrict__ W, const float* __restrict__ bias,
    const float* __restrict__ zn, float* __restrict__ attn)
{
  const int t = threadIdx.x, wave = t >> 6, lane = t & 63;
  const int o = blockIdx.x * 4 + wave;
  const float4* Wr = (const float4*)(W + ((size_t)2 * E_DIM + o) * E_DIM);
  const float4* zr = (const float4*)(zn + (size_t)(o >> 7) * E_DIM);
  float a = 0.f;
#pragma unroll
  for (int k = 0; k < 4; ++k) {
    float4 wv = Wr[lane + 64 * k];
    float4 zv = zr[lane + 64 * k];
    a += wv.x * zv.x + wv.y * zv.y + wv.z * zv.z + wv.w * zv.w;
  }
#pragma unroll
  for (int m = 1; m < 64; m <<= 1) a += __shfl_xor(a, m, 64);
  if (lane == 0) attn[o] = a + bias[2 * E_DIM + o];
}

// ---------------- out[e] = Wo[e] . attn + bo[e] ----------------
__global__ __launch_bounds__(256) void proj_o(
    const float* __restrict__ Wo, const float* __restrict__ bo,
    const float* __restrict__ attn, float* __restrict__ out)
{
  const int t = threadIdx.x, wave = t >> 6, lane = t & 63;
  const int o = blockIdx.x * 4 + wave;
  const float4* Wr = (const float4*)(Wo + (size_t)o * E_DIM);
  const float4* vr = (const float4*)attn;
  float a = 0.f;
#pragma unroll
  for (int k = 0; k < 4; ++k) {
    float4 wv = Wr[lane + 64 * k];
    float4 vv = vr[lane + 64 * k];
    a += wv.x * vv.x + wv.y * vv.y + wv.z * vv.z + wv.w * vv.w;
  }
#pragma unroll
  for (int m = 1; m < 64; m <<= 1) a += __shfl_xor(a, m, 64);
  if (lane == 0) out[o] = a + bo[o];
}

extern "C" void kernel_launch(void* const* d_in, const int* in_sizes, int n_in,
                              void* d_out, int out_size, void* d_ws, size_t ws_size,
                              hipStream_t stream)
{
  const float* x  = (const float*)d_in[0];   // [32768,1024]
  const float* Wi = (const float*)d_in[1];   // [3072,1024]
  const float* bi = (const float*)d_in[2];   // [3072]
  const float* Wo = (const float*)d_in[3];   // [1024,1024]
  const float* bo = (const float*)d_in[4];   // [1024]
  float* out = (float*)d_out;                // [1024] fp32

  // workspace layout (bytes)
  char* ws = (char*)d_ws;
  float* q     = (float*)(ws + 0);          // 1024 f
  float* P_T   = (float*)(ws + 4096);       // 8192 f
  float* zn    = (float*)(ws + 36864);      // 8192 f
  float* attn  = (float*)(ws + 69632);      // 1024 f
  float* psumw = (float*)(ws + 73728);      // nblk*8 f (<= 16 KB)
  float* wbuf  = (float*)(ws + 90112);      // 32768*8 f = 1 MB
  const size_t pz_off = 1179648;
  float* pz    = (float*)(ws + pz_off);     // nblk*8192 f

  // pick partial-block count from available workspace (constant across calls)
  int nblk = 128;
  if (ws_size >= pz_off + (size_t)512 * NHEAD * E_DIM * 4) nblk = 512;
  else if (ws_size >= pz_off + (size_t)256 * NHEAD * E_DIM * 4) nblk = 256;
  const int rows_per_blk = L_SEQ / nblk;

  proj_q    <<<256, 256, 0, stream>>>(Wi, bi, x, q);
  make_p    <<<dim3(8, 8), 128, 0, stream>>>(Wi, q, P_T);
  score_pass<<<nblk, 512, 0, stream>>>(x, P_T, wbuf, psumw, rows_per_blk);
  accum_pass<<<nblk, 512, 0, stream>>>(x, wbuf, pz, rows_per_blk);
  reduce_z  <<<256, 256, 0, stream>>>(pz, psumw, zn, nblk);
  proj_v    <<<256, 256, 0, stream>>>(Wi, bi, zn, attn);
  proj_o    <<<256, 256, 0, stream>>>(Wo, bo, attn, out);
}

// Round 5
// 241.213 us; speedup vs baseline: 1.4885x; 1.4885x over previous
//
#include <hip/hip_runtime.h>
#include <math.h>

// Single-query MHA, algebraically collapsed:
//   s[l,h] = x_l . p_h         (p_h = Wk_h^T q_h / sqrt(D); k-bias shift cancels in softmax)
//   z_h    = sum_l softmax(s)_lh * x_l
//   attn   = Wv z + bv ; out = Wo attn + bo
// All fp32. No max-subtraction needed: |s| ~ N(0,1), max ~ 5 << 88 (fp32 exp range).
//
// v5 (attn_fused4): ONE pass over x. Per 8-row tile: each wave loads one row
// (registers), stages it to LDS, scores 8 heads, transpose-reduces (10 shfl),
// writes w to LDS; phase B accumulates from the LDS x_tile (no global re-read).
// Register discipline: empirically on this toolchain __launch_bounds__(512,N)
// caps VGPRs at 256/N (R1: N=2 -> 128; R4: N=4 -> 64 + 220MB spill WRITE).
// This kernel needs ~90 regs -> (512,2). LDS 64.3KB -> 2 blocks/CU.

#define L_SEQ   32768
#define E_DIM   1024
#define NHEAD   8
#define HDIM    128
#define TILE_R  8
#define WAVES_M 8            // 512 threads

// ---------------- q = Wq x0 + bq : wave-per-output GEMV ----------------
__global__ __launch_bounds__(256) void proj_q(
    const float* __restrict__ W, const float* __restrict__ bias,
    const float* __restrict__ x, float* __restrict__ q)
{
  const int t = threadIdx.x, wave = t >> 6, lane = t & 63;
  const int o = blockIdx.x * 4 + wave;
  const float4* Wr = (const float4*)(W + (size_t)o * E_DIM);
  const float4* xr = (const float4*)x;   // row 0 of x
  float a = 0.f;
#pragma unroll
  for (int k = 0; k < 4; ++k) {
    float4 wv = Wr[lane + 64 * k];
    float4 xv = xr[lane + 64 * k];
    a += wv.x * xv.x + wv.y * xv.y + wv.z * xv.z + wv.w * xv.w;
  }
#pragma unroll
  for (int m = 1; m < 64; m <<= 1) a += __shfl_xor(a, m, 64);
  if (lane == 0) q[o] = a + bias[o];
}

// ---------------- P_T[h][e] = (1/sqrt(D)) sum_d q[h*128+d] * Wk[h*128+d][e] ----------------
__global__ __launch_bounds__(128) void make_p(
    const float* __restrict__ W, const float* __restrict__ q,
    float* __restrict__ P_T)
{
  const int h = blockIdx.y;
  const int e = blockIdx.x * 128 + threadIdx.x;
  const float* qh = q + h * HDIM;                              // lane-uniform (scalarized)
  const float* Wb = W + ((size_t)E_DIM + (size_t)h * HDIM) * E_DIM + e;  // Wk block rows
  float a0 = 0.f, a1 = 0.f, a2 = 0.f, a3 = 0.f;
#pragma unroll 4
  for (int d = 0; d < HDIM; d += 4) {
    a0 += qh[d + 0] * Wb[(size_t)(d + 0) * E_DIM];
    a1 += qh[d + 1] * Wb[(size_t)(d + 1) * E_DIM];
    a2 += qh[d + 2] * Wb[(size_t)(d + 2) * E_DIM];
    a3 += qh[d + 3] * Wb[(size_t)(d + 3) * E_DIM];
  }
  P_T[h * E_DIM + e] = ((a0 + a1) + (a2 + a3)) * 0.08838834764831845f;   // 1/sqrt(128)
}

// ---------------- fused single-pass scores + softmax-weights + weighted-x ----------------
__global__ __launch_bounds__(512, 2) void attn_fused4(
    const float* __restrict__ x,
    const float* __restrict__ P_T,       // [8][1024]
    float* __restrict__ partial_z,       // [nblk][8][1024]
    float* __restrict__ partial_sumw,    // [nblk][8]
    int rows_per_blk)
{
  __shared__ __align__(16) float P_lds[NHEAD * E_DIM];        // 32 KB
  __shared__ __align__(16) float x_tile[TILE_R][E_DIM];       // 32 KB
  __shared__ __align__(16) float w_tile[TILE_R][NHEAD];       // 256 B
  __shared__ __align__(16) float sw_stage[WAVES_M][NHEAD];

  const int t = threadIdx.x;
  const int wave = t >> 6;
  const int lane = t & 63;
  const size_t row0 = (size_t)blockIdx.x * rows_per_blk;
  const int ntiles = rows_per_blk / TILE_R;

  // transpose-reduce mapping for 8 values / 3 splitting levels:
  // lane ends with head j = b0*4 + b1*2 + b2 (bk = bit k of lane)
  const int h_l = ((lane & 1) << 2) | (((lane >> 1) & 1) << 1) | ((lane >> 2) & 1);

  // stage P into LDS (2048 float4 / 512 threads)
  {
    const float4* src = (const float4*)P_T;
    float4* dst = (float4*)P_lds;
#pragma unroll
    for (int i = 0; i < 4; ++i) dst[i * 512 + t] = src[i * 512 + t];
  }
  __syncthreads();

  float acc[16];
#pragma unroll
  for (int i = 0; i < 16; ++i) acc[i] = 0.f;
  float sumw_own = 0.f;

  // preload tile 0: wave w owns row (row0 + w)
  float4 xv[4];
  {
    const float4* xr = (const float4*)(x + (row0 + wave) * E_DIM);
#pragma unroll
    for (int k = 0; k < 4; ++k) xv[k] = xr[lane + 64 * k];
  }

  for (int tile = 0; tile < ntiles; ++tile) {
    const size_t trow = row0 + (size_t)tile * TILE_R;

    // stage this wave's row into LDS
    {
      float4* xd = (float4*)&x_tile[wave][0];
#pragma unroll
      for (int k = 0; k < 4; ++k) xd[lane + 64 * k] = xv[k];
    }

    // issue next tile's global load early (completes during phase B)
    float4 xn[4];
    if (tile + 1 < ntiles) {
      const float4* xr = (const float4*)(x + (trow + TILE_R + wave) * E_DIM);
#pragma unroll
      for (int k = 0; k < 4; ++k) xn[k] = xr[lane + 64 * k];
    }

    // 8 head-dots from registers vs LDS P
    float v[NHEAD];
#pragma unroll
    for (int h = 0; h < NHEAD; ++h) {
      const float4* pr = (const float4*)(P_lds + h * E_DIM);
      float a = 0.f;
#pragma unroll
      for (int k = 0; k < 4; ++k) {
        float4 p = pr[lane + 64 * k];
        a += xv[k].x * p.x + xv[k].y * p.y + xv[k].z * p.z + xv[k].w * p.w;
      }
      v[h] = a;
    }

    // transpose-butterfly: 3 splitting levels (8->1 values/lane), then 3 plain
#pragma unroll
    for (int lev = 0; lev < 3; ++lev) {
      const int d = 1 << lev;
      const int half = 4 >> lev;
#pragma unroll
      for (int i = 0; i < half; ++i) {
        float lo = v[i], hi = v[i + half];
        float keep = (lane & d) ? hi : lo;
        float oth  = (lane & d) ? lo : hi;
        v[i] = keep + __shfl_xor(oth, d, 64);
      }
    }
    float tot = v[0];
    tot += __shfl_xor(tot, 8, 64);
    tot += __shfl_xor(tot, 16, 64);
    tot += __shfl_xor(tot, 32, 64);

    const float w = __expf(tot);
    sumw_own += w;                        // lanes>=8 replicate; only lanes<8 stored
    if (lane < 8) w_tile[wave][h_l] = w;

    __syncthreads();   // x_tile + w_tile ready

    // phase B: thread t accumulates cols {2t,2t+1} x 8 heads over the 8 rows (LDS)
#pragma unroll
    for (int r = 0; r < TILE_R; ++r) {
      const float2 xv2 = *(const float2*)&x_tile[r][2 * t];
      const float4* wp = (const float4*)&w_tile[r][0];
      const float4 wlo = wp[0], whi = wp[1];
      acc[0]  += wlo.x * xv2.x;  acc[1]  += wlo.x * xv2.y;
      acc[2]  += wlo.y * xv2.x;  acc[3]  += wlo.y * xv2.y;
      acc[4]  += wlo.z * xv2.x;  acc[5]  += wlo.z * xv2.y;
      acc[6]  += wlo.w * xv2.x;  acc[7]  += wlo.w * xv2.y;
      acc[8]  += whi.x * xv2.x;  acc[9]  += whi.x * xv2.y;
      acc[10] += whi.y * xv2.x;  acc[11] += whi.y * xv2.y;
      acc[12] += whi.z * xv2.x;  acc[13] += whi.z * xv2.y;
      acc[14] += whi.w * xv2.x;  acc[15] += whi.w * xv2.y;
    }

    __syncthreads();   // phase-B readers done before next tile overwrites x_tile

    if (tile + 1 < ntiles) {
#pragma unroll
      for (int k = 0; k < 4; ++k) xv[k] = xn[k];
    }
  }

  // write block partial z directly from registers (coalesced per head)
  {
    float* zd = partial_z + (size_t)blockIdx.x * (NHEAD * E_DIM) + 2 * t;
#pragma unroll
    for (int h = 0; h < NHEAD; ++h)
      *(float2*)(zd + h * E_DIM) = make_float2(acc[2 * h], acc[2 * h + 1]);
  }

  // sum-of-weights: lanes 0..7 hold this wave's per-head totals
  if (lane < 8) sw_stage[wave][h_l] = sumw_own;
  __syncthreads();
  if (t < NHEAD) {
    float s = 0.f;
#pragma unroll
    for (int wv = 0; wv < WAVES_M; ++wv) s += sw_stage[wv][t];
    partial_sumw[blockIdx.x * NHEAD + t] = s;
  }
}

// ---------------- reduce partials: zn[h][e] = sum_b pz / sum_b psumw ----------------
__global__ __launch_bounds__(256) void reduce_z(
    const float* __restrict__ partial_z,
    const float* __restrict__ partial_sumw,
    float* __restrict__ zn, int nblk)
{
  __shared__ float red[256];
  __shared__ __align__(16) float swst[4][NHEAD];
  __shared__ float sumw_s[NHEAD];
  const int t = threadIdx.x;
  const int lane = t & 63, wave = t >> 6;

  float sw[NHEAD];
#pragma unroll
  for (int h = 0; h < NHEAD; ++h) sw[h] = 0.f;
  for (int b = t; b < nblk; b += 256) {
    const float4* p = (const float4*)(partial_sumw + (size_t)b * NHEAD);
    float4 a0 = p[0], a1 = p[1];
    sw[0] += a0.x; sw[1] += a0.y; sw[2] += a0.z; sw[3] += a0.w;
    sw[4] += a1.x; sw[5] += a1.y; sw[6] += a1.z; sw[7] += a1.w;
  }
#pragma unroll
  for (int m = 1; m < 64; m <<= 1) {
#pragma unroll
    for (int h = 0; h < NHEAD; ++h) sw[h] += __shfl_xor(sw[h], m, 64);
  }
  if (lane == 0) {
#pragma unroll
    for (int h = 0; h < NHEAD; ++h) swst[wave][h] = sw[h];
  }
  __syncthreads();
  if (t < NHEAD) sumw_s[t] = swst[0][t] + swst[1][t] + swst[2][t] + swst[3][t];

  const int o = blockIdx.x * 32 + (t & 31);
  const int g = t >> 5;
  float a = 0.f;
  for (int b = g; b < nblk; b += 8) a += partial_z[(size_t)b * (NHEAD * E_DIM) + o];
  red[t] = a;
  __syncthreads();
  if (t < 32) {
    float s2 = 0.f;
#pragma unroll
    for (int gg = 0; gg < 8; ++gg) s2 += red[gg * 32 + t];
    const int oo = blockIdx.x * 32 + t;
    zn[oo] = s2 / sumw_s[oo >> 10];   // oo = h*1024 + e
  }
}

// ---------------- attn[o] = Wv[o] . zn[h(o)] + bv[o] ----------------
__global__ __launch_bounds__(256) void proj_v(
    const float* __restrict__ W, const float* __restrict__ bias,
    const float* __restrict__ zn, float* __restrict__ attn)
{
  const int t = threadIdx.x, wave = t >> 6, lane = t & 63;
  const int o = blockIdx.x * 4 + wave;
  const float4* Wr = (const float4*)(W + ((size_t)2 * E_DIM + o) * E_DIM);
  const float4* zr = (const float4*)(zn + (size_t)(o >> 7) * E_DIM);
  float a = 0.f;
#pragma unroll
  for (int k = 0; k < 4; ++k) {
    float4 wv = Wr[lane + 64 * k];
    float4 zv = zr[lane + 64 * k];
    a += wv.x * zv.x + wv.y * zv.y + wv.z * zv.z + wv.w * zv.w;
  }
#pragma unroll
  for (int m = 1; m < 64; m <<= 1) a += __shfl_xor(a, m, 64);
  if (lane == 0) attn[o] = a + bias[2 * E_DIM + o];
}

// ---------------- out[e] = Wo[e] . attn + bo[e] ----------------
__global__ __launch_bounds__(256) void proj_o(
    const float* __restrict__ Wo, const float* __restrict__ bo,
    const float* __restrict__ attn, float* __restrict__ out)
{
  const int t = threadIdx.x, wave = t >> 6, lane = t & 63;
  const int o = blockIdx.x * 4 + wave;
  const float4* Wr = (const float4*)(Wo + (size_t)o * E_DIM);
  const float4* vr = (const float4*)attn;
  float a = 0.f;
#pragma unroll
  for (int k = 0; k < 4; ++k) {
    float4 wv = Wr[lane + 64 * k];
    float4 vv = vr[lane + 64 * k];
    a += wv.x * vv.x + wv.y * vv.y + wv.z * vv.z + wv.w * vv.w;
  }
#pragma unroll
  for (int m = 1; m < 64; m <<= 1) a += __shfl_xor(a, m, 64);
  if (lane == 0) out[o] = a + bo[o];
}

extern "C" void kernel_launch(void* const* d_in, const int* in_sizes, int n_in,
                              void* d_out, int out_size, void* d_ws, size_t ws_size,
                              hipStream_t stream)
{
  const float* x  = (const float*)d_in[0];   // [32768,1024]
  const float* Wi = (const float*)d_in[1];   // [3072,1024]
  const float* bi = (const float*)d_in[2];   // [3072]
  const float* Wo = (const float*)d_in[3];   // [1024,1024]
  const float* bo = (const float*)d_in[4];   // [1024]
  float* out = (float*)d_out;                // [1024] fp32

  // workspace layout (bytes)
  char* ws = (char*)d_ws;
  float* q     = (float*)(ws + 0);          // 1024 f
  float* P_T   = (float*)(ws + 4096);       // 8192 f
  float* zn    = (float*)(ws + 36864);      // 8192 f
  float* attn  = (float*)(ws + 69632);      // 1024 f
  float* psumw = (float*)(ws + 73728);      // nblk*8 f (<= 16 KB)
  const size_t pz_off = 90112;
  float* pz    = (float*)(ws + pz_off);     // nblk*8192 f

  // pick partial-block count from available workspace (constant across calls)
  int nblk = 128;
  if (ws_size >= pz_off + (size_t)512 * NHEAD * E_DIM * 4) nblk = 512;
  else if (ws_size >= pz_off + (size_t)256 * NHEAD * E_DIM * 4) nblk = 256;
  const int rows_per_blk = L_SEQ / nblk;

  proj_q     <<<256, 256, 0, stream>>>(Wi, bi, x, q);
  make_p     <<<dim3(8, 8), 128, 0, stream>>>(Wi, q, P_T);
  attn_fused4<<<nblk, 512, 0, stream>>>(x, P_T, pz, psumw, rows_per_blk);
  reduce_z   <<<256, 256, 0, stream>>>(pz, psumw, zn, nblk);
  proj_v     <<<256, 256, 0, stream>>>(Wi, bi, zn, attn);
  proj_o     <<<256, 256, 0, stream>>>(Wo, bo, attn, out);
}